// Round 6
// baseline (422.846 us; speedup 1.0000x reference)
//
#include <hip/hip_runtime.h>
#include <hip/hip_bf16.h>

// Non-local block, B=8 C=512 H=W=64, IC=256, N2=HW=4096, N=2048 (folded).
//
// Round-6:
//  - convtr v3: 4 tiles/block, register-prefetch pipeline (loads overlap stores)
//  - ov_k stages G rows permuted plane-major -> OVT [n][h*256+ic]
//  - mask_k K=256 with plain bf16 w_mask (zero-interleave removed)
//  - scores_k XCD 4x4-supertile swizzle for L2 locality

typedef __attribute__((ext_vector_type(8))) short short8;
typedef __attribute__((ext_vector_type(4))) short short4v;
typedef __attribute__((ext_vector_type(4))) float f32x4;

enum { EPI_BF16 = 0, EPI_BF16_BIAS = 1 };

__device__ __forceinline__ short f2bf(float f) {
  union { __hip_bfloat16 h; short s; } u; u.h = __float2bfloat16(f); return u.s;
}
__device__ __forceinline__ float bf2f(short s) {
  union { short s; __hip_bfloat16 h; } u; u.s = s; return __bfloat162float(u.h);
}

__device__ __forceinline__ void async_ld16(const void* g, void* l) {
  __builtin_amdgcn_global_load_lds(
      (const __attribute__((address_space(1))) unsigned int*)(unsigned long long)g,
      (__attribute__((address_space(3))) unsigned int*)(unsigned int)(unsigned long long)l,
      16, 0, 0);
}

// ---------------- 8-wave 128x128 GEMM: C[i][j] = sum_k A[i][k]*BT[j][k] ----
template<int EPI>
__global__ __launch_bounds__(512, 4)
void gemm8(const short* __restrict__ Ag, long sA, int lda,
           const short* __restrict__ Bg, long sB, int ldb,
           short* __restrict__ Cg, long sC, int ldc,
           int K, const float* __restrict__ bias)
{
  __shared__ __align__(16) short As[128 * 32];
  __shared__ __align__(16) short Bs[128 * 32];
  const int bz = blockIdx.z;
  const short* A = Ag + (long)bz * sA;
  const short* B = Bg + (long)bz * sB;
  const int m0 = blockIdx.y * 128;
  const int n0 = blockIdx.x * 128;
  const int t = threadIdx.x;
  const int wv = t >> 6, ln = t & 63;
  const int wr = wv >> 1, wc = wv & 1;
  const int fr = ln & 15, q8 = (ln >> 4) * 8;
  const int rowA = t >> 2, kc = (t & 3) * 8;

  f32x4 acc[2][4];
  #pragma unroll
  for (int i = 0; i < 2; i++)
    #pragma unroll
    for (int j = 0; j < 4; j++)
      #pragma unroll
      for (int r = 0; r < 4; r++) acc[i][j][r] = 0.f;

  for (int kk = 0; kk < K; kk += 32) {
    async_ld16(A + (long)(m0 + rowA) * lda + kk + kc, As + wv * 512);
    async_ld16(B + (long)(n0 + rowA) * ldb + kk + kc, Bs + wv * 512);
    __syncthreads();
    short8 af[2], bfr[4];
    #pragma unroll
    for (int mi = 0; mi < 2; mi++) af[mi] = *(const short8*)&As[(wr * 32 + mi * 16 + fr) * 32 + q8];
    #pragma unroll
    for (int ni = 0; ni < 4; ni++) bfr[ni] = *(const short8*)&Bs[(wc * 64 + ni * 16 + fr) * 32 + q8];
    #pragma unroll
    for (int mi = 0; mi < 2; mi++)
      #pragma unroll
      for (int ni = 0; ni < 4; ni++)
        acc[mi][ni] = __builtin_amdgcn_mfma_f32_16x16x32_bf16(af[mi], bfr[ni], acc[mi][ni], 0, 0, 0);
    __syncthreads();
  }

  const int colb = n0 + wc * 64 + fr;
  const int rowb = m0 + wr * 32 + (ln >> 4) * 4;
  #pragma unroll
  for (int mi = 0; mi < 2; mi++)
    #pragma unroll
    for (int r = 0; r < 4; r++) {
      const int mr = rowb + mi * 16 + r;
      float badd = 0.f;
      if constexpr (EPI == EPI_BF16_BIAS) badd = bias[mr];
      #pragma unroll
      for (int ni = 0; ni < 4; ni++)
        Cg[(long)bz * sC + (long)mr * ldc + colb + ni * 16] = f2bf(acc[mi][ni][r] + badd);
    }
}

// ---------------- OV GEMM, XCD swizzle + plane-major G row permutation -----
// OVT[b][n][c'] = sum_m E[n][m]*Gv[perm(c')][m],  perm(c') = 2*(c'&255)+(c'>>8)
// so OVT cols 0..255 = even channels (h=0, ic-major), 256..511 = odd (h=1).
__global__ __launch_bounds__(512, 4)
void ov_k(const short* __restrict__ Eg, const short* __restrict__ Gg,
          short* __restrict__ Cg)
{
  const int L = blockIdx.x;
  const int xcd = L & 7, k = L >> 3;
  const int slab = xcd + ((k >> 2) << 3);   // 0..127
  const int bz = slab >> 4, by = slab & 15, bx = k & 3;

  __shared__ __align__(16) short As[128 * 32];
  __shared__ __align__(16) short Bs[128 * 32];
  const short* A = Eg + ((long)bz << 22);
  const short* B = Gg + ((long)bz << 20);
  const int m0 = by * 128;
  const int n0 = bx * 128;
  const int t = threadIdx.x;
  const int wv = t >> 6, ln = t & 63;
  const int wr = wv >> 1, wc = wv & 1;
  const int fr = ln & 15, q8 = (ln >> 4) * 8;
  const int rowA = t >> 2, kc = (t & 3) * 8;

  // permuted B row for this lane's staging
  const int jB = n0 + rowA;                       // c' in [0,512)
  const long boff = (long)(jB & 255) * 4096 + (long)(jB >> 8) * 2048;

  f32x4 acc[2][4];
  #pragma unroll
  for (int i = 0; i < 2; i++)
    #pragma unroll
    for (int j = 0; j < 4; j++)
      #pragma unroll
      for (int r = 0; r < 4; r++) acc[i][j][r] = 0.f;

  for (int kk = 0; kk < 2048; kk += 32) {
    async_ld16(A + (long)(m0 + rowA) * 2048 + kk + kc, As + wv * 512);
    async_ld16(B + boff + kk + kc, Bs + wv * 512);
    __syncthreads();
    short8 af[2], bfr[4];
    #pragma unroll
    for (int mi = 0; mi < 2; mi++) af[mi] = *(const short8*)&As[(wr * 32 + mi * 16 + fr) * 32 + q8];
    #pragma unroll
    for (int ni = 0; ni < 4; ni++) bfr[ni] = *(const short8*)&Bs[(wc * 64 + ni * 16 + fr) * 32 + q8];
    #pragma unroll
    for (int mi = 0; mi < 2; mi++)
      #pragma unroll
      for (int ni = 0; ni < 4; ni++)
        acc[mi][ni] = __builtin_amdgcn_mfma_f32_16x16x32_bf16(af[mi], bfr[ni], acc[mi][ni], 0, 0, 0);
    __syncthreads();
  }

  const int colb = n0 + wc * 64 + fr;
  const int rowb = m0 + wr * 32 + (ln >> 4) * 4;
  #pragma unroll
  for (int mi = 0; mi < 2; mi++)
    #pragma unroll
    for (int r = 0; r < 4; r++) {
      const int mr = rowb + mi * 16 + r;
      #pragma unroll
      for (int ni = 0; ni < 4; ni++)
        Cg[((long)bz << 20) + (long)mr * 512 + colb + ni * 16] = f2bf(acc[mi][ni][r]);
    }
}

// ---------------- pixel-major phi/theta conv: TPT2 = imgT · W^T + b --------
__global__ __launch_bounds__(256)
void conv_pt(const short* __restrict__ imgT,
             const short* __restrict__ wth, const short* __restrict__ wph,
             const float* __restrict__ bth, const float* __restrict__ bph,
             short* __restrict__ TPT2)
{
  __shared__ __align__(16) short As[128 * 32];
  __shared__ __align__(16) short Bs[128 * 32];
  const int m0 = blockIdx.y * 128;
  const int n0 = blockIdx.x * 128;
  const bool isphi = blockIdx.y >= 256;
  const short* A = imgT + (long)m0 * 512;
  const short* B = isphi ? wph : wth;
  const float* bias = isphi ? bph : bth;
  const int t = threadIdx.x;
  const int wv = t >> 6, ln = t & 63;
  const int wm = (wv >> 1) * 64, wn = (wv & 1) * 64;
  const int fr = ln & 15, q8 = (ln >> 4) * 8;
  const int rowA = t >> 2, kc = (t & 3) * 8;

  f32x4 acc[4][4];
  #pragma unroll
  for (int i = 0; i < 4; i++)
    #pragma unroll
    for (int j = 0; j < 4; j++)
      #pragma unroll
      for (int r = 0; r < 4; r++) acc[i][j][r] = 0.f;

  for (int kk = 0; kk < 512; kk += 32) {
    #pragma unroll
    for (int s = 0; s < 2; s++) {
      async_ld16(A + (long)(s * 64 + rowA) * 512 + kk + kc, As + (s * 256 + wv * 64) * 8);
      async_ld16(B + (long)(n0 + s * 64 + rowA) * 512 + kk + kc, Bs + (s * 256 + wv * 64) * 8);
    }
    __syncthreads();
    short8 af[4], bfr[4];
    #pragma unroll
    for (int mi = 0; mi < 4; mi++) af[mi] = *(const short8*)&As[(wm + mi * 16 + fr) * 32 + q8];
    #pragma unroll
    for (int ni = 0; ni < 4; ni++) bfr[ni] = *(const short8*)&Bs[(wn + ni * 16 + fr) * 32 + q8];
    #pragma unroll
    for (int mi = 0; mi < 4; mi++)
      #pragma unroll
      for (int ni = 0; ni < 4; ni++)
        acc[mi][ni] = __builtin_amdgcn_mfma_f32_16x16x32_bf16(af[mi], bfr[ni], acc[mi][ni], 0, 0, 0);
    __syncthreads();
  }

  const int colb = n0 + wn + fr;
  const int rowb = m0 + wm + (ln >> 4) * 4;
  float cb[4];
  #pragma unroll
  for (int ni = 0; ni < 4; ni++) cb[ni] = bias[colb + ni * 16];
  #pragma unroll
  for (int mi = 0; mi < 4; mi++)
    #pragma unroll
    for (int r = 0; r < 4; r++) {
      const long mr = rowb + mi * 16 + r;
      #pragma unroll
      for (int ni = 0; ni < 4; ni++)
        TPT2[mr * 256 + colb + ni * 16] = f2bf(acc[mi][ni][r] + cb[ni]);
    }
}

// ---------------- scores: E = exp(TT2·PT2^T), XCD supertile swizzle --------
// grid (256,1,8). 16x16 tile grid decomposed into 4x4 supertiles; each XCD
// owns 2 supertiles (A+B slabs = 1MB << 4MB L2).
__global__ __launch_bounds__(256)
void scores_k(const short* __restrict__ TT2, const short* __restrict__ PT2,
              short* __restrict__ ST, float* __restrict__ pstats)
{
  __shared__ __align__(16) short As[128 * 32];
  __shared__ __align__(16) short Bs[128 * 32];
  const int L = blockIdx.x;
  const int xcd = L & 7, s = L >> 3;        // s 0..31
  const int st = xcd + 8 * (s >> 4);        // supertile 0..15
  const int inner = s & 15;
  const int by = (st >> 2) * 4 + (inner >> 2);
  const int bx = (st & 3) * 4 + (inner & 3);
  const int bz = blockIdx.z;
  const int t = threadIdx.x;
  const int wv = t >> 6, ln = t & 63;
  const int wm = (wv >> 1) * 64, wn = (wv & 1) * 64;
  const int fr = ln & 15, q8 = (ln >> 4) * 8;
  const int rowA = t >> 2, kc = (t & 3) * 8;

  f32x4 acc[4][4];
  #pragma unroll
  for (int i = 0; i < 4; i++)
    #pragma unroll
    for (int j = 0; j < 4; j++)
      #pragma unroll
      for (int r = 0; r < 4; r++) acc[i][j][r] = 0.f;

  #pragma unroll
  for (int h = 0; h < 2; h++) {
    const short* Aseg = TT2 + ((long)(bz * 4096 + h * 2048 + by * 128)) * 256;
    const short* Bseg = PT2 + ((long)(bz * 4096 + h * 2048 + bx * 128)) * 256;
    for (int kk = 0; kk < 256; kk += 32) {
      #pragma unroll
      for (int s2 = 0; s2 < 2; s2++) {
        async_ld16(Aseg + (long)(s2 * 64 + rowA) * 256 + kk + kc, As + (s2 * 256 + wv * 64) * 8);
        async_ld16(Bseg + (long)(s2 * 64 + rowA) * 256 + kk + kc, Bs + (s2 * 256 + wv * 64) * 8);
      }
      __syncthreads();
      short8 af[4], bfr[4];
      #pragma unroll
      for (int mi = 0; mi < 4; mi++) af[mi] = *(const short8*)&As[(wm + mi * 16 + fr) * 32 + q8];
      #pragma unroll
      for (int ni = 0; ni < 4; ni++) bfr[ni] = *(const short8*)&Bs[(wn + ni * 16 + fr) * 32 + q8];
      #pragma unroll
      for (int mi = 0; mi < 4; mi++)
        #pragma unroll
        for (int ni = 0; ni < 4; ni++)
          acc[mi][ni] = __builtin_amdgcn_mfma_f32_16x16x32_bf16(af[mi], bfr[ni], acc[mi][ni], 0, 0, 0);
      __syncthreads();
    }
  }

  const int colb = bx * 128 + wn + fr;
  const int rowb = by * 128 + wm + (ln >> 4) * 4;
  short* base = ST + ((long)bz << 22);
  float ps[4] = {0.f, 0.f, 0.f, 0.f};
  #pragma unroll
  for (int mi = 0; mi < 4; mi++)
    #pragma unroll
    for (int r = 0; r < 4; r++) {
      const long mr = rowb + mi * 16 + r;
      #pragma unroll
      for (int ni = 0; ni < 4; ni++) {
        float e = __expf(acc[mi][ni][r]);
        base[mr * 2048 + colb + ni * 16] = f2bf(e);
        ps[ni] += e;
      }
    }
  #pragma unroll
  for (int ni = 0; ni < 4; ni++) {
    ps[ni] += __shfl_xor(ps[ni], 16);
    ps[ni] += __shfl_xor(ps[ni], 32);
  }
  float* part = (float*)As;
  if (ln < 16) {
    #pragma unroll
    for (int ni = 0; ni < 4; ni++)
      part[(wv >> 1) * 128 + wn + ni * 16 + fr] = ps[ni];
  }
  __syncthreads();
  if (t < 128)
    pstats[((long)(bz * 16 + by)) * 2048 + bx * 128 + t] = part[t] + part[128 + t];
}

// ---------------- reduce 16 partials -> invZ per column --------------------
__global__ __launch_bounds__(256)
void zfinal(const float* __restrict__ pstats, float* __restrict__ invZ)
{
  const int g = blockIdx.x * 256 + threadIdx.x;
  const int b = g >> 11, col = g & 2047;
  float S = 0.f;
  #pragma unroll
  for (int rc = 0; rc < 16; rc++) S += pstats[((long)(b * 16 + rc)) * 2048 + col];
  invZ[g] = 1.f / S;
}

// ---------------- G *= invZ[m] (in place) ----------------------------------
__global__ __launch_bounds__(256)
void g_scale(short* __restrict__ G, const float* __restrict__ invZ)
{
  const long base = ((long)blockIdx.x * 256 + threadIdx.x) * 8;
  const int bz = (int)(base >> 20);
  const int n2 = (int)(base & 4095);
  const float* z = invZ + bz * 2048 + (n2 & 2047);
  short8 v = *(short8*)&G[base];
  f32x4 z0 = *(const f32x4*)z;
  f32x4 z1 = *(const f32x4*)(z + 4);
  #pragma unroll
  for (int j = 0; j < 4; j++) { v[j] = f2bf(bf2f(v[j]) * z0[j]); v[4 + j] = f2bf(bf2f(v[4 + j]) * z1[j]); }
  *(short8*)&G[base] = v;
}

// ---------------- mask GEMM v2: K=256, plane-major OVT ---------------------
// out[o][px] = sum_ic Wm[o][ic]*OVT[px&2047][(px>>11)*256+ic] + b + x
__global__ __launch_bounds__(256)
void mask_k(const short* __restrict__ Wm, const short* __restrict__ OVT,
            const float* __restrict__ bmask, const float* __restrict__ x,
            float* __restrict__ out)
{
  __shared__ __align__(16) short As[128 * 32];
  __shared__ __align__(16) short Bs[128 * 32];
  const int bz = blockIdx.z;
  const int n0 = blockIdx.x * 128;        // px base
  const int m0 = blockIdx.y * 128;        // o base
  const short* B = OVT + ((long)bz << 20) + (long)(n0 & 2047) * 512
                   + ((n0 >= 2048) ? 256 : 0);
  const int t = threadIdx.x;
  const int wv = t >> 6, ln = t & 63;
  const int wm = (wv >> 1) * 64, wn = (wv & 1) * 64;
  const int fr = ln & 15, q8 = (ln >> 4) * 8;
  const int rowA = t >> 2, kc = (t & 3) * 8;

  f32x4 acc[4][4];
  #pragma unroll
  for (int i = 0; i < 4; i++)
    #pragma unroll
    for (int j = 0; j < 4; j++)
      #pragma unroll
      for (int r = 0; r < 4; r++) acc[i][j][r] = 0.f;

  for (int kk = 0; kk < 256; kk += 32) {
    #pragma unroll
    for (int s = 0; s < 2; s++) {
      async_ld16(Wm + (long)(m0 + s * 64 + rowA) * 256 + kk + kc, As + (s * 256 + wv * 64) * 8);
      async_ld16(B + (long)(s * 64 + rowA) * 512 + kk + kc, Bs + (s * 256 + wv * 64) * 8);
    }
    __syncthreads();
    short8 af[4], bfr[4];
    #pragma unroll
    for (int mi = 0; mi < 4; mi++) af[mi] = *(const short8*)&As[(wm + mi * 16 + fr) * 32 + q8];
    #pragma unroll
    for (int ni = 0; ni < 4; ni++) bfr[ni] = *(const short8*)&Bs[(wn + ni * 16 + fr) * 32 + q8];
    #pragma unroll
    for (int mi = 0; mi < 4; mi++)
      #pragma unroll
      for (int ni = 0; ni < 4; ni++)
        acc[mi][ni] = __builtin_amdgcn_mfma_f32_16x16x32_bf16(af[mi], bfr[ni], acc[mi][ni], 0, 0, 0);
    __syncthreads();
  }

  const int colb = n0 + wn + fr;
  const int rowb = m0 + wm + (ln >> 4) * 4;
  #pragma unroll
  for (int mi = 0; mi < 4; mi++)
    #pragma unroll
    for (int r = 0; r < 4; r++) {
      const int mr = rowb + mi * 16 + r;
      const float badd = bmask[mr];
      const long rbase = ((long)bz * 512 + mr) * 4096;
      #pragma unroll
      for (int ni = 0; ni < 4; ni++) {
        const int cc = colb + ni * 16;
        out[rbase + cc] = acc[mi][ni][r] + badd + x[rbase + cc];
      }
    }
}

// ---------------- weight prep: 4x plain f32->bf16 convert ------------------
__global__ __launch_bounds__(256)
void wconv2(const float* w_phi, const float* w_theta, const float* w_g,
            const float* w_mask,
            short* wph, short* wth, short* wg, short* wm)
{
  const int seg = blockIdx.x >> 6;
  const int blk = blockIdx.x & 63;
  const int i0 = blk * 2048 + threadIdx.x * 8;
  const float* s = seg == 0 ? w_phi : seg == 1 ? w_theta : seg == 2 ? w_g : w_mask;
  short* d = seg == 0 ? wph : seg == 1 ? wth : seg == 2 ? wg : wm;
  f32x4 a = *(const f32x4*)&s[i0];
  f32x4 b = *(const f32x4*)&s[i0 + 4];
  short8 o;
  #pragma unroll
  for (int j = 0; j < 4; j++) { o[j] = f2bf(a[j]); o[4 + j] = f2bf(b[j]); }
  *(short8*)&d[i0] = o;
}

// ---------------- convert + transpose v3: pipelined multi-tile -------------
// img[b][512][4096] f32 -> imgT[b][4096][512] bf16. Block: 4 tiles of
// 64px x 128c; prefetch tile i+1's loads before tile i's store phase.
__global__ __launch_bounds__(256)
void convtr(const float* __restrict__ x, const float* __restrict__ y,
            short* __restrict__ xT, short* __restrict__ yT)
{
  __shared__ __align__(16) short Ts[64 * 136];
  const int z = blockIdx.z;
  const float* src = (z < 8 ? x : y) + (long)(z & 7) * 512 * 4096;
  short* dst = (z < 8 ? xT : yT) + (long)(z & 7) * 4096 * 512;
  const int c0 = blockIdx.y * 128;
  const int nb = blockIdx.x * 256;     // 4 tiles of 64 px
  const int t = threadIdx.x;
  const int i16 = t & 15;
  const int rbase = t >> 4;
  const int sw = (i16 & 3) << 3;

  f32x4 v[8];
  #pragma unroll
  for (int p = 0; p < 8; p++)
    v[p] = *(const f32x4*)&src[(long)(c0 + p * 16 + rbase) * 4096 + nb + i16 * 4];

  for (int it = 0; it < 4; it++) {
    const int n0 = nb + it * 64;
    __syncthreads();   // previous tile's readers done
    #pragma unroll
    for (int p = 0; p < 8; p++) {
      const int cs = (p * 16 + rbase) ^ sw;
      #pragma unroll
      for (int j = 0; j < 4; j++)
        Ts[(i16 * 4 + j) * 136 + cs] = f2bf(v[p][j]);
    }
    __syncthreads();
    if (it < 3) {       // prefetch next tile; overlaps LDS reads + stores below
      #pragma unroll
      for (int p = 0; p < 8; p++)
        v[p] = *(const f32x4*)&src[(long)(c0 + p * 16 + rbase) * 4096 + (n0 + 64) + i16 * 4];
    }
    #pragma unroll
    for (int q = 0; q < 4; q++) {
      const int idx = q * 256 + t;
      const int px = idx >> 4;
      const int p16 = idx & 15;
      const int sw2 = ((px >> 2) & 3) << 3;
      short8 o = *(const short8*)&Ts[px * 136 + ((p16 * 8) ^ sw2)];
      *(short8*)&dst[(long)(n0 + px) * 512 + c0 + p16 * 8] = o;
    }
  }
}

// ---------------------------------------------------------------------------
extern "C" void kernel_launch(void* const* d_in, const int* in_sizes, int n_in,
                              void* d_out, int out_size, void* d_ws, size_t ws_size,
                              hipStream_t stream)
{
  (void)in_sizes; (void)n_in; (void)out_size; (void)ws_size;
  const float* x       = (const float*)d_in[0];
  const float* y       = (const float*)d_in[1];
  const float* w_phi   = (const float*)d_in[2];
  const float* b_phi   = (const float*)d_in[3];
  const float* w_theta = (const float*)d_in[4];
  const float* b_theta = (const float*)d_in[5];
  const float* w_g     = (const float*)d_in[6];
  const float* b_g     = (const float*)d_in[7];
  const float* w_mask  = (const float*)d_in[8];
  const float* b_mask  = (const float*)d_in[9];
  float* out = (float*)d_out;

  char* ws = (char*)d_ws;
  const long MB = 1L << 20;
  short* wph  = (short*)(ws + 0);
  short* wth  = (short*)(ws + 256 * 1024);
  short* wg   = (short*)(ws + 512 * 1024);
  short* wm   = (short*)(ws + 768 * 1024);
  short* xT   = (short*)(ws + 2 * MB);    // [8][4096][512], 32MB
  short* yT   = (short*)(ws + 34 * MB);   // 32MB
  short* TPT2 = (short*)(ws + 66 * MB);   // [65536][256], 32MB
  short* G    = (short*)(ws + 98 * MB);   // [8][256][4096], 16MB
  short* ST   = (short*)(ws + 2 * MB);    // [8][2048][2048] E, 64MB (over xT/yT)
  float* pstats = (float*)(ws + 114 * MB);
  float* invZ   = (float*)(ws + 115 * MB);
  short* OVT  = (short*)(ws + 66 * MB);   // [8][2048][512], 16MB (over TPT2)

  dim3 blk(256, 1, 1);
  dim3 blk8(512, 1, 1);

  wconv2<<<dim3(256, 1, 1), blk, 0, stream>>>(w_phi, w_theta, w_g, w_mask,
                                              wph, wth, wg, wm);
  convtr<<<dim3(16, 4, 16), blk, 0, stream>>>(x, y, xT, yT);

  conv_pt<<<dim3(2, 512, 1), blk, 0, stream>>>(xT, wth, wph, b_theta, b_phi, TPT2);

  gemm8<EPI_BF16_BIAS><<<dim3(32, 2, 8), blk8, 0, stream>>>(
      wg, 0, 512, xT, 4096L * 512, 512, G, 1048576L, 4096, 512, b_g);

  scores_k<<<dim3(256, 1, 8), blk, 0, stream>>>(TPT2, TPT2 + 32768L * 256, ST, pstats);
  zfinal<<<dim3(64, 1, 1), blk, 0, stream>>>(pstats, invZ);
  g_scale<<<dim3(4096, 1, 1), blk, 0, stream>>>(G, invZ);

  ov_k<<<dim3(512, 1, 1), blk8, 0, stream>>>(ST, G, OVT);

  mask_k<<<dim3(32, 4, 8), blk, 0, stream>>>(wm, OVT, b_mask, x, out);
}